// Round 14
// baseline (182.140 us; speedup 1.0000x reference)
//
#include <hip/hip_runtime.h>

#define Bsz 1024
#define Nn 256
#define Fdim 8
#define Eedge 1024
#define OUTC 128
#define CADV 192
#define CTOT 256
#define Ktot 32768   // Nn * OUTC
#define ASTR 40      // a_s/b_s LDS row stride in bf16 (32+8): 16B-aligned, 2-way banks
#define XSTR 24      // rw_s row stride (48 B = 12-bank stride -> 2-way, free)

typedef __attribute__((ext_vector_type(8))) short short8;
typedef __attribute__((ext_vector_type(4))) float float4v;

static __device__ inline unsigned short f2bf(float f) {
  union { float f; unsigned u; } v; v.f = f;
  unsigned r = v.u + 0x7FFFu + ((v.u >> 16) & 1u);  // round-nearest-even
  return (unsigned short)(r >> 16);
}
static __device__ inline uint4 pack8(const unsigned short* b) {
  uint4 v;
  v.x = (unsigned)b[0] | ((unsigned)b[1] << 16);
  v.y = (unsigned)b[2] | ((unsigned)b[3] << 16);
  v.z = (unsigned)b[4] | ((unsigned)b[5] << 16);
  v.w = (unsigned)b[6] | ((unsigned)b[7] << 16);
  return v;
}
// HW packed f32->bf16 RNE convert: dst = bf(a) | bf(b)<<16, ONE VALU op.
static __device__ inline unsigned cvtpk(float a, float b) {
  unsigned r;
  asm("v_cvt_pk_bf16_f32 %0, %1, %2" : "=v"(r) : "v"(a), "v"(b));
  return r;
}
static __device__ inline float hi_of(unsigned p)  {  // bf2f(low half)
  union { unsigned u; float f; } v; v.u = p << 16; return v.f;
}
static __device__ inline float hi2_of(unsigned p) {  // bf2f(high half)
  union { unsigned u; float f; } v; v.u = p & 0xFFFF0000u; return v.f;
}
// Build this lane's A-gen x-fragment: lq 0/2 -> bf16-hi of the 8 floats,
// lq 1 -> bf16 of the residual (lo), lq 3 -> don't-care (wf is 0 there).
static __device__ inline short8 make_frag(float4 a, float4 b, int lq) {
  union { unsigned u[4]; short8 s; } uu;
  unsigned h0 = cvtpk(a.x, a.y), h1 = cvtpk(a.z, a.w);
  unsigned h2 = cvtpk(b.x, b.y), h3 = cvtpk(b.z, b.w);
  uu.u[0] = h0; uu.u[1] = h1; uu.u[2] = h2; uu.u[3] = h3;
  if (lq == 1) {
    uu.u[0] = cvtpk(a.x - hi_of(h0), a.y - hi2_of(h0));
    uu.u[1] = cvtpk(a.z - hi_of(h1), a.w - hi2_of(h1));
    uu.u[2] = cvtpk(b.x - hi_of(h2), b.y - hi2_of(h2));
    uu.u[3] = cvtpk(b.z - hi_of(h3), b.w - hi2_of(h3));
  }
  return uu.s;
}

// ---------------------------------------------------------------------------
// K1 (R13-proven): tail x16 (theta + S scatter + feat0 b=0 correction)
// + wt transpose (linear layout; K2 LDS-stages it).
// ---------------------------------------------------------------------------
__global__ __launch_bounds__(256) void prep_feat_kernel(
    const float* __restrict__ x, const int* __restrict__ ei,
    const float* __restrict__ w1, const float* __restrict__ b1,
    const float* __restrict__ w2, const float* __restrict__ b2,
    const float* __restrict__ rootw, const float* __restrict__ convb,
    const float* __restrict__ advw, const float* __restrict__ v1w,
    unsigned short* __restrict__ wt, unsigned short* __restrict__ feat0)
{
  __shared__ __align__(16) char smem[20480];
  int bid = blockIdx.x, t = threadIdx.x;

  if (bid < 16) {
    // ---- tail x16: theta slice + redundant scatter S + feat0 o-slice ----
    float* fs   = (float*)smem;
    float* h_s  = fs;            // 64
    float* rw_s = fs + 64;       // 64
    float* th_s = fs + 128;      // 64
    float* pt_s = fs + 192;      // 256
    float* S_s  = fs + 448;      // 2048
    int*   flag = (int*)(fs + 2496);
    int obase = bid * 8;

    if (t < 64) {
      h_s[t]  = fmaxf(w1[t] + b1[t], 0.f);
      rw_s[t] = rootw[(t >> 3) * OUTC + obase + (t & 7)];
    }
    for (int i = t; i < Nn * Fdim; i += 256) S_s[i] = 0.f;
    if (t == 0) {
      int z = 0;
      for (int i = 1; i < 16; i += 2) z |= ei[i];
      *flag = (z == 0);  // little-endian int64 detection
    }
    __syncthreads();
    int is64 = *flag;

    {  // theta slice: 64 cols x 64-deep reduction across 4 waves
      int l = t & 63, g = t >> 6;
      int c = (l >> 3) * 128 + obase + (l & 7);
      float p = 0.f;
#pragma unroll
      for (int j = 0; j < 16; ++j)
        p += h_s[g * 16 + j] * w2[(size_t)(g * 16 + j) * 1024 + c];
      pt_s[t] = p;
    }
    int srcs[4], tgts[4];
#pragma unroll
    for (int q = 0; q < 4; ++q) {
      int e = t + q * 256;
      if (is64) { srcs[q] = ei[2 * e]; tgts[q] = ei[2 * (Eedge + e)]; }
      else      { srcs[q] = ei[e];     tgts[q] = ei[Eedge + e]; }
      srcs[q] &= 255; tgts[q] &= 255;
    }
    __syncthreads();
    if (t < 64) {
      int c = (t >> 3) * 128 + obase + (t & 7);
      th_s[t] = b2[c] + pt_s[t] + pt_s[t + 64] + pt_s[t + 128] + pt_s[t + 192];
    }
#pragma unroll
    for (int q = 0; q < 4; ++q) {
      const float* xp = x + srcs[q] * Fdim;
#pragma unroll
      for (int f = 0; f < Fdim; ++f)
        atomicAdd(&S_s[tgts[q] * Fdim + f], xp[f]);
    }
    __syncthreads();
    {  // feat0 slice: thread t = node n, 8 o-columns
      int n = t;
      const float* xp = x + n * Fdim;
      float4 xa = *(const float4*)xp;
      float4 xb = *(const float4*)(xp + 4);
      float xv[8] = {xa.x, xa.y, xa.z, xa.w, xb.x, xb.y, xb.z, xb.w};
      float sv[8];
#pragma unroll
      for (int f = 0; f < 8; ++f) sv[f] = S_s[n * Fdim + f];
      unsigned short buf[8];
#pragma unroll
      for (int oi = 0; oi < 8; ++oi) {
        float z = convb[obase + oi];
#pragma unroll
        for (int f = 0; f < 8; ++f)
          z += xv[f] * rw_s[f * 8 + oi] + sv[f] * th_s[f * 8 + oi];
        buf[oi] = f2bf(fmaxf(z, 0.f));
      }
      *(uint4*)(feat0 + (size_t)n * OUTC + obase) = pack8(buf);
    }
  } else {
    // ---- wt transpose: 32-deep load batch, LDS-staged, coalesced flush ----
    unsigned short* st = (unsigned short*)smem;  // 20 KB
    int kt = bid - 16, c = t;
    const float* src; int stride, col;
    if (c < CADV) { src = advw; stride = CADV; col = c; }
    else          { src = v1w;  stride = 64;   col = c - CADV; }
    float v[32];
#pragma unroll
    for (int i = 0; i < 32; ++i)
      v[i] = src[(size_t)(kt * 32 + i) * stride + col];
    unsigned pk[16];
#pragma unroll
    for (int i = 0; i < 16; ++i) pk[i] = cvtpk(v[2 * i], v[2 * i + 1]);
#pragma unroll
    for (int p = 0; p < 4; ++p) {
      uint4 w4; w4.x = pk[p * 4]; w4.y = pk[p * 4 + 1];
      w4.z = pk[p * 4 + 2]; w4.w = pk[p * 4 + 3];
      *(uint4*)(st + c * ASTR + p * 8) = w4;
    }
    __syncthreads();
    uint4* dst = (uint4*)(wt + (size_t)kt * (CTOT * 32));
    for (int r = 0; r < 4; ++r) {
      int s = r * 256 + c;        // lane-consecutive -> coalesced
      dst[s] = *(const uint4*)(st + (s >> 2) * ASTR + (s & 3) * 8);
    }
  }
}

// ---------------------------------------------------------------------------
// K2 (R23): proven R13 dataflow, tile 64x128, FOUR blocks/CU.
// Every prior lever (load order R14, B-direct R15, write traffic R22, VALU
// R21, async DMA R20) left gemm frozen at ~43us -> the binding term is the
// per-iter barrier-lockstep stall with only 2 barrier domains/CU (m233
// 2-phase signature). This config: BN 256->128 (b_s dbuf 40->20 KB) and
// A-gen x-feed moved from LDS to per-thread registers (each A-gen thread
// owns ONE fixed x row; x_s deleted) -> 36.5 KB/block -> 4 blocks/CU =
// 4 independent barrier domains, 32 waves/CU. Dataflow/sync unchanged.
// Grid dim3(NS=32, 16, 2): XCD = ch%8; 32 blocks/chunk share wt slabs in L2.
// ---------------------------------------------------------------------------
__global__ __launch_bounds__(512, 4) void gemm_mfma(
    const float* __restrict__ x, const unsigned short* __restrict__ wt,
    const float* __restrict__ rootw, const float* __restrict__ convb,
    const unsigned short* __restrict__ feat0, float* __restrict__ part,
    int iters, int ns)
{
  __shared__ short a_s[2][64 * ASTR];    // 10 KB
  __shared__ short b_s[2][128 * ASTR];   // 20 KB
  __shared__ short rw_s[128 * XSTR];     // 6 KB  [o][wh0..7 | wl0..7 | pad]
  __shared__ float convb_s[128];         // 0.5 KB
  int t = threadIdx.x;
  int ch = blockIdx.x;   // K chunk (XCD = ch%8)
  int mb = blockIdx.y;   // 0..15
  int nc = blockIdx.z;   // 0..1 column half
  int wave = t >> 6, lane = t & 63;
  int wm = wave >> 2, wn = wave & 3;   // 2(m) x 4(n) wave grid over 64x128
  int lm = lane & 15, lq = lane >> 4;

  float4v acc[2][2];
#pragma unroll
  for (int i = 0; i < 2; ++i)
#pragma unroll
    for (int j = 0; j < 2; ++j) acc[i][j] = (float4v)0.f;

  int kt0 = ch * iters;
  int iters4 = iters >> 2;          // nodes in this chunk (8)
  int n0 = ch * iters4;             // first node
  int wr0 = (t >> 2) * ASTR + (t & 3) * 8;   // b_s write: 512 thr x 16 B
  int grow = (wave & 3) * 16 + lm;  // A-gen batch row (0..63)
  int gtt  = wave >> 2;             // A-gen o-subtile within slab (0..1)

  // ---- prologue staging ----
  if (t < 128) {
    float wv[8];
#pragma unroll
    for (int f = 0; f < 8; ++f) wv[f] = rootw[f * OUTC + t];
    unsigned ph[4];
#pragma unroll
    for (int i = 0; i < 4; ++i) ph[i] = cvtpk(wv[2 * i], wv[2 * i + 1]);
    float wl[8];
#pragma unroll
    for (int i = 0; i < 4; ++i) {
      wl[2 * i]     = wv[2 * i]     - hi_of(ph[i]);
      wl[2 * i + 1] = wv[2 * i + 1] - hi2_of(ph[i]);
    }
    unsigned pl[4];
#pragma unroll
    for (int i = 0; i < 4; ++i) pl[i] = cvtpk(wl[2 * i], wl[2 * i + 1]);
    uint4 wh4; wh4.x = ph[0]; wh4.y = ph[1]; wh4.z = ph[2]; wh4.w = ph[3];
    uint4 wl4; wl4.x = pl[0]; wl4.y = pl[1]; wl4.z = pl[2]; wl4.w = pl[3];
    *(uint4*)(rw_s + t * XSTR)     = wh4;
    *(uint4*)(rw_s + t * XSTR + 8) = wl4;
    convb_s[t] = convb[t];
  }
  // this thread's fixed A-gen x row (registers; x_s deleted)
  const float* xrow = x + ((size_t)(mb * 64 + grow) * Nn) * Fdim;
  float4 xa0 = *(const float4*)(xrow + (size_t)n0 * Fdim);
  float4 xb0 = *(const float4*)(xrow + (size_t)n0 * Fdim + 4);
  short8 xf_cur = make_frag(xa0, xb0, lq);
  short8 xf_next = xf_cur;
  float4 xpa = xa0, xpb = xb0;
  if (iters4 > 1) {
    xpa = *(const float4*)(xrow + (size_t)(n0 + 1) * Fdim);
    xpb = *(const float4*)(xrow + (size_t)(n0 + 1) * Fdim + 4);
  }
  __syncthreads();

  // stage A-subtile for iter 0 (slab kt0, node n0): 8 waves x 1 gen-MFMA
  {
    int ot = gtt;                        // kt0 % 4 == 0
    short8 wf = (short8)0;
    if (lq <= 1)      wf = *(const short8*)(rw_s + (ot * 16 + lm) * XSTR);
    else if (lq == 2) wf = *(const short8*)(rw_s + (ot * 16 + lm) * XSTR + 8);
    float4v c = __builtin_amdgcn_mfma_f32_16x16x32_bf16(wf, xf_cur, (float4v)0.f, 0, 0, 0);
    int o0 = ot * 16 + lq * 4;
    float4 cb = *(const float4*)(convb_s + o0);
    unsigned d0 = cvtpk(fmaxf(c[0] + cb.x, 0.f), fmaxf(c[1] + cb.y, 0.f));
    unsigned d1 = cvtpk(fmaxf(c[2] + cb.z, 0.f), fmaxf(c[3] + cb.w, 0.f));
    if (mb == 0 && grow == 0) {
      const unsigned* f0p = (const unsigned*)(feat0 + ((size_t)n0 * OUTC + o0));
      d0 = f0p[0]; d1 = f0p[1];
    }
    uint2 dd; dd.x = d0; dd.y = d1;
    *(uint2*)(a_s[0] + grow * ASTR + gtt * 16 + lq * 4) = dd;
  }

  // preload B tile 0 (this block's column half of slab kt0)
  const uint4* gB = (const uint4*)wt;
  uint4 vb0 = gB[(size_t)kt0 * 1024 + nc * 512 + t];

  for (int kk = 0; kk < iters; ++kk) {
    int g = kk & 3, grp = kk >> 2;
    short* bb = b_s[kk & 1];
    *(uint4*)(bb + wr0) = vb0;
    if (g == 0 && grp + 1 < iters4) {   // prefetch next node's x row
      xpa = *(const float4*)(xrow + (size_t)(n0 + grp + 1) * Fdim);
      xpb = *(const float4*)(xrow + (size_t)(n0 + grp + 1) * Fdim + 4);
    }
    if (g == 3 && grp + 1 < iters4)
      xf_next = make_frag(xpa, xpb, lq);
    if (kk + 1 < iters)
      vb0 = gB[(size_t)(kt0 + kk + 1) * 1024 + nc * 512 + t];
    __syncthreads();

    // main MFMA on tile kk
    short* ab = a_s[kk & 1];
    short8 aF[2];
#pragma unroll
    for (int i = 0; i < 2; ++i)
      aF[i] = *(const short8*)(ab + (wm * 32 + i * 16 + lm) * ASTR + lq * 8);
#pragma unroll
    for (int j = 0; j < 2; ++j) {
      short8 bF = *(const short8*)(bb + (wn * 32 + j * 16 + lm) * ASTR + lq * 8);
#pragma unroll
      for (int i = 0; i < 2; ++i)
        acc[i][j] = __builtin_amdgcn_mfma_f32_16x16x32_bf16(bF, aF[i], acc[i][j], 0, 0, 0);
    }

    // stage A-subtile for iter kk+1 (8 waves x 1 gen-MFMA)
    if (kk + 1 < iters) {
      int kn = kk + 1;
      int g2 = kn & 3, grp2 = kn >> 2;
      int node2 = n0 + grp2;
      short* ad = a_s[kn & 1];
      short8 xf = (g == 3) ? xf_next : xf_cur;
      int ot = g2 * 2 + gtt;
      short8 wf = (short8)0;
      if (lq <= 1)      wf = *(const short8*)(rw_s + (ot * 16 + lm) * XSTR);
      else if (lq == 2) wf = *(const short8*)(rw_s + (ot * 16 + lm) * XSTR + 8);
      float4v c = __builtin_amdgcn_mfma_f32_16x16x32_bf16(wf, xf, (float4v)0.f, 0, 0, 0);
      int o0 = ot * 16 + lq * 4;
      float4 cb = *(const float4*)(convb_s + o0);
      unsigned d0 = cvtpk(fmaxf(c[0] + cb.x, 0.f), fmaxf(c[1] + cb.y, 0.f));
      unsigned d1 = cvtpk(fmaxf(c[2] + cb.z, 0.f), fmaxf(c[3] + cb.w, 0.f));
      if (mb == 0 && grow == 0) {
        const unsigned* f0p = (const unsigned*)(feat0 + ((size_t)node2 * OUTC + o0));
        d0 = f0p[0]; d1 = f0p[1];
      }
      uint2 dd; dd.x = d0; dd.y = d1;
      *(uint2*)(ad + grow * ASTR + gtt * 16 + lq * 4) = dd;
      if (g == 3) xf_cur = xf_next;
    }
  }

  // epilogue: part layout [b][ch][c]; per-lane dwordx4
  float* pb = part + ((size_t)(mb * 64) * ns + ch) * CTOT + nc * 128;
#pragma unroll
  for (int i = 0; i < 2; ++i) {
    int m = wm * 32 + i * 16 + lm;
#pragma unroll
    for (int j = 0; j < 2; ++j) {
      int c = wn * 32 + j * 16 + lq * 4;
      *(float4v*)(pb + (size_t)m * ns * CTOT + c) = acc[i][j];
    }
  }
}

// ---------------------------------------------------------------------------
// K3 (R19-proven): float4-vectorized split-K reduction + LDS combine,
// then biases+relu, val MLP, dueling combine. ns=32 -> 32 KB read/block.
// ---------------------------------------------------------------------------
__global__ __launch_bounds__(256) void final_kernel(
    const float* __restrict__ part, int ns,
    const float* __restrict__ advb, const float* __restrict__ v1b,
    const float* __restrict__ v2w, const float* __restrict__ v2b,
    const float* __restrict__ v3w, const float* __restrict__ v3b,
    float* __restrict__ out)
{
  __shared__ float4v red_s[4][64];   // 4 KB
  __shared__ float adv_s[CADV];
  __shared__ float v1_s[64];
  __shared__ float val2_s[64];
  __shared__ float val3_s[64];
  int b = blockIdx.x, t = threadIdx.x;
  int q = t & 63, r0 = t >> 6;       // col-quad, row-group
  const float4v* p4 = (const float4v*)(part + (size_t)b * ns * CTOT);
  float4v s4 = (float4v)0.f;
  for (int i = r0; i < ns; i += 4) s4 += p4[i * 64 + q];
  red_s[r0][q] = s4;
  __syncthreads();
  float s;
  {
    const float* rs = (const float*)red_s;   // [r][256] floats
    s = rs[t] + rs[256 + t] + rs[512 + t] + rs[768 + t];
  }
  if (t < CADV) adv_s[t] = fmaxf(s + advb[t], 0.f);
  else          v1_s[t - CADV] = fmaxf(s + v1b[t - CADV], 0.f);
  __syncthreads();
  if (t < 64) {
    float a = v2b[t];
#pragma unroll
    for (int i = 0; i < 64; ++i) a += v1_s[i] * v2w[i * 64 + t];
    val2_s[t] = fmaxf(a, 0.f);
  }
  __syncthreads();
  if (t < 64) {
    float a = v3b[t];
#pragma unroll
    for (int j = 0; j < 64; ++j) a += val2_s[j] * v3w[j * 64 + t];
    val3_s[t] = a;
  }
  __syncthreads();
  if (t < CADV) {
    int d = t / 3;
    float mean = (adv_s[d * 3] + adv_s[d * 3 + 1] + adv_s[d * 3 + 2]) * (1.f / 3.f);
    out[(size_t)b * CADV + t] = val3_s[d] + adv_s[t] - mean;
  }
}

extern "C" void kernel_launch(void* const* d_in, const int* in_sizes, int n_in,
                              void* d_out, int out_size, void* d_ws, size_t ws_size,
                              hipStream_t stream)
{
  (void)in_sizes; (void)n_in; (void)out_size;
  const float* x     = (const float*)d_in[0];
  const int*   ei    = (const int*)d_in[1];
  const float* w1    = (const float*)d_in[2];
  const float* b1    = (const float*)d_in[3];
  const float* w2    = (const float*)d_in[4];
  const float* b2    = (const float*)d_in[5];
  const float* rootw = (const float*)d_in[6];
  const float* convb = (const float*)d_in[7];
  const float* advw  = (const float*)d_in[8];
  const float* advb  = (const float*)d_in[9];
  const float* v1w   = (const float*)d_in[10];
  const float* v1b   = (const float*)d_in[11];
  const float* v2w   = (const float*)d_in[12];
  const float* v2b   = (const float*)d_in[13];
  const float* v3w   = (const float*)d_in[14];
  const float* v3b   = (const float*)d_in[15];
  float* out = (float*)d_out;

  const size_t f0B = 131072;                    // feat0 64 KB (padded)
  const size_t wtB = (size_t)Ktot * CTOT * 2;   // 16.8 MB

  int NS = 32;   // x16 mb x2 nc; part = 32 MB (ws >= 81 MB proven)
  while (NS > 8 && f0B + wtB + (size_t)NS * Bsz * CTOT * 4 > ws_size)
    NS >>= 1;

  unsigned short* feat0 = (unsigned short*)d_ws;
  unsigned short* wtp   = (unsigned short*)((char*)d_ws + f0B);
  float* part = (float*)((char*)d_ws + f0B + wtB);

  prep_feat_kernel<<<1040, 256, 0, stream>>>(x, ei, w1, b1, w2, b2, rootw,
                                             convb, advw, v1w, wtp, feat0);
  gemm_mfma<<<dim3(NS, 16, 2), 512, 0, stream>>>(x, wtp, rootw, convb, feat0,
                                                 part, 1024 / NS, NS);
  final_kernel<<<Bsz, 256, 0, stream>>>(part, NS, advb, v1b, v2w, v2b, v3w, v3b, out);
}